// Round 11
// baseline (2534.275 us; speedup 1.0000x reference)
//
#include <hip/hip_runtime.h>
#include <stdint.h>

// LSTM: B=256, T=1024, I=64, H=256, O=1. fp32 in/out, bf16 MFMA internally.
//
// Round-22 = R21 (2486us, best multi-block) with the weight-residency fix
// its VGPR_Count=144 demands. wf[4][10] needs 160 VGPRs; at 144 the
// allocator spilled ~60-80 VGPRs of weights -> every step re-read ~1KB/lane
// of scratch. Key insight: Phase A's weights (x + own quarter, kc 0..3)
// run UNDER THE POLL SHADOW and are latency-tolerant -> move them to LDS
// (64KB, packed bf16 frags at startup). Only Phase C's peer weights
// (kc 4..9 = 24 frags = 96 VGPRs) stay register-resident, because they sit
// on the serial publish->MALL->detect->compute path. Register demand ~170
// < 248 -> zero spill; serial path never touches scratch or L2.
//
// Topology (R21): 128 blocks = 32 groups x 4 quarters x 256 thr. Wave wv
// owns rows j*256 + q*64 + wv*16 + ln (ALL 4 gates j); c/h update fully
// in-register (lanes lk<2 hold C rows m = lk*4+r). Fan-in 3.
//
// Pipelined recurrence: Phase A (bias + x + own quarter: 16 MFMA, LDS
// weights) under the in-flight poll; Phase C (peers: 24 MFMA, register
// weights) + nonlin + publish on the serial cycle. x prefetched one step
// ahead (clamped).
//
// Communication (R11/R13-verified, byte-identical to R21): relaxed
// AGENT-scope (MALL) 8B units {2xbf16 h pair, tag=step}; quiet pipelined
// poll (probes issued before Phase A, reloads issued BEFORE s_sleep(1),
// satisfied lanes stop loading, SENT_CAP dead-latch =>
// wrong-answer-not-hang). Tag poison 0xAAAAAAAA != live tags 1..1024 =>
// no ws init. Final h (tag 1024) -> separate never-polled clean region at
// 2*UPP. Parity/staleness: tag-t units (parity t&1) are overwritten by tag
// t+2 only after the writer's poll(t+1), which needs every peer's
// publish(t+1), which follows that peer's poll(t).
//
// LDS: w_lds 64KB (64 frags: (wv*4+j)*4+s, 1KB each; lane l holds 16B at
// l*16; slot s: 0..1 = W_ih k=s*32.., 2..3 = W_hh own-quarter cols) +
// h_lds[2][8][272] double buffer (8.7KB) = 72.7KB.
// iter t: Phase A reads own cols of buf[t&1]; capture writes PEER cols of
// buf[t&1] (disjoint); MID-barrier; Phase C reads peer cols; update writes
// own h(t+1) to buf[(t+1)&1] + publishes; END-barrier.
//
// Unit index in group: q*256 + m*32 + pair (pair = local hid/2).

#define T_ 1024
#define I_ 64
#define H_ 256
#define NGROUP 32
#define NQ 4
#define MB 8      /* batches per group */
#define QH 64     /* hidden units per block (quarter) */
#define HROW 272  /* padded h_lds row (ushorts), 544 B */

#define UNITS_PER_GROUP 1024                       /* 8B units per step */
#define UNITS_PER_PARITY (NGROUP * UNITS_PER_GROUP)
#define SENT_CAP (1 << 16)   /* dead-latch: ~64k sleep-sweeps */

typedef float floatx4 __attribute__((ext_vector_type(4)));
typedef __bf16 bf16x8 __attribute__((ext_vector_type(8)));
typedef unsigned short ushortx8 __attribute__((ext_vector_type(8)));
typedef unsigned int uint32;
typedef unsigned long long u64;

__device__ __forceinline__ float bf2f(uint32 u16) {
  uint32 u = u16 << 16;
  return __builtin_bit_cast(float, u);
}
__device__ __forceinline__ bf16x8 packbf8(floatx4 a, floatx4 b) {
  bf16x8 r;
  r[0] = (__bf16)a[0]; r[1] = (__bf16)a[1];
  r[2] = (__bf16)a[2]; r[3] = (__bf16)a[3];
  r[4] = (__bf16)b[0]; r[5] = (__bf16)b[1];
  r[6] = (__bf16)b[2]; r[7] = (__bf16)b[3];
  return r;
}
__device__ __forceinline__ float fast_sig(float v) {
  return 1.0f / (1.0f + __expf(-v));
}
__device__ __forceinline__ float fast_tanh(float v) {
  float e = __expf(2.0f * v);
  return 1.0f - 2.0f / (e + 1.0f);
}
__device__ __forceinline__ u64 aload64(const u64* p) {
  return __hip_atomic_load(p, __ATOMIC_RELAXED, __HIP_MEMORY_SCOPE_AGENT);
}
__device__ __forceinline__ void astore64(u64* p, u64 v) {
  __hip_atomic_store(p, v, __ATOMIC_RELAXED, __HIP_MEMORY_SCOPE_AGENT);
}

__global__ __launch_bounds__(256, 1) void lstm_main(
    const float* __restrict__ x, const float* __restrict__ W_ih,
    const float* __restrict__ W_hh, const float* __restrict__ b_ih,
    const float* __restrict__ b_hh, u64* __restrict__ units) {
  const int tid = threadIdx.x;
  const int bid = blockIdx.x;
  const int q = bid >> 5;     // quarter 0..3
  const int g = bid & 31;     // group 0..31
  const int wv = tid >> 6;    // wave 0..3 -> 16-hid sub-block
  const int lane = tid & 63;
  const int ln = lane & 15;   // MFMA n (hid) / A row (batch, dup)
  const int lk = lane >> 4;   // MFMA k-subgroup / C row group

  __shared__ __align__(16) unsigned short w_lds[64 * 512];  // 64KB frags
  __shared__ __align__(16) unsigned short h_lds[2][MB][HROW];

  const size_t gbase = (size_t)g * UNITS_PER_GROUP;
  const int q1 = (q + 1) & 3, q2 = (q + 2) & 3, q3 = (q + 3) & 3;

  // zero both h_lds buffers (h_0 = 0; also clears pad)
  {
    uint32* p = (uint32*)&h_lds[0][0][0];
    for (int i = tid; i < 2 * MB * HROW / 2; i += 256) p[i] = 0u;
  }

  // ---- Phase-A weights (x + own quarter) -> LDS frags, once ----
  // frag id = (wv*4 + j)*4 + s; lane slice at lane*8 (ushorts).
  unsigned short* const wl = w_lds + (size_t)(wv * 16) * 512 + lane * 8;
  // ---- Phase-C weights (3 peer quarters) -> registers wf[4][6] ----
  bf16x8 wf[4][6];
  float bias[4];
#pragma unroll
  for (int j = 0; j < 4; ++j) {
    const int row = j * 256 + q * QH + wv * 16 + ln;
    bias[j] = b_ih[row] + b_hh[row];
    const float* wih = W_ih + (size_t)row * I_;
    const float* whh = W_hh + (size_t)row * H_;
#pragma unroll
    for (int s = 0; s < 4; ++s) {  // LDS slots: 0..1 x, 2..3 own quarter
      const float* src = (s < 2) ? (wih + s * 32 + lk * 8)
                                 : (whh + q * QH + (s - 2) * 32 + lk * 8);
      floatx4 f0 = *(const floatx4*)src;
      floatx4 f1 = *(const floatx4*)(src + 4);
      *(bf16x8*)(wl + (j * 4 + s) * 512) = packbf8(f0, f1);
    }
#pragma unroll
    for (int kc = 0; kc < 6; ++kc) {  // reg slots: q1,q1,q2,q2,q3,q3
      const float* src;
      if (kc < 2)      src = whh + q1 * QH + kc * 32 + lk * 8;
      else if (kc < 4) src = whh + q2 * QH + (kc - 2) * 32 + lk * 8;
      else             src = whh + q3 * QH + (kc - 4) * 32 + lk * 8;
      floatx4 f0 = *(const floatx4*)src;
      floatx4 f1 = *(const floatx4*)(src + 4);
      wf[j][kc] = packbf8(f0, f1);
    }
  }

  const int mb = ln & 7;                       // batch row (m>=8 duplicates)
  const float* xrow = x + ((size_t)(g * MB + mb)) * T_ * I_ + lk * 8;
  // poll roles: thread tid polls unit tid of each peer quarter
  const int pm = tid >> 5;                     // batch of polled units 0..7
  const int pp2 = 2 * (tid & 31);              // 2*pair
  const int pc1 = q1 * QH + pp2, pc2 = q2 * QH + pp2, pc3 = q3 * QH + pp2;
  // publish roles (lanes lk<2, even ln)
  const int opair = wv * 8 + (ln >> 1);
  const int ocol = q * QH + wv * 16 + ln;
  // HREAD col bases
  const int hb_own = q * QH;
  const int hb1 = q1 * QH, hb2 = q2 * QH, hb3 = q3 * QH;

  floatx4 c_reg = (floatx4){0.f, 0.f, 0.f, 0.f};

  // preload x_0
  floatx4 xf0, xf1, xf2, xf3;
  xf0 = *(const floatx4*)(xrow);
  xf1 = *(const floatx4*)(xrow + 4);
  xf2 = *(const floatx4*)(xrow + 32);
  xf3 = *(const floatx4*)(xrow + 36);

  __syncthreads();  // w_lds + h_lds ready

#define HREAD(BASE, OFF)                                                    \
  __builtin_bit_cast(bf16x8, *(const ushortx8*)(hrow + (BASE) + (OFF)*32 + \
                                                lk * 8))
#define WLD(J, S)                                                           \
  __builtin_bit_cast(bf16x8, *(const ushortx8*)(wl + ((J)*4 + (S)) * 512))
#define MFMA4L(A, S)                                                        \
  _Pragma("unroll") for (int j = 0; j < 4; ++j) acc[j] =                    \
      __builtin_amdgcn_mfma_f32_16x16x32_bf16((A), WLD(j, S), acc[j], 0, 0, \
                                              0);
#define MFMA4R(A, KC)                                                       \
  _Pragma("unroll") for (int j = 0; j < 4; ++j) acc[j] =                    \
      __builtin_amdgcn_mfma_f32_16x16x32_bf16((A), wf[j][KC], acc[j], 0, 0, \
                                              0);

#pragma unroll 1
  for (int t = 0; t < T_; ++t) {
    bf16x8 a0 = packbf8(xf0, xf1);
    bf16x8 a1 = packbf8(xf2, xf3);
    {  // prefetch x_{t+1} (clamped; hides under Phase A + poll)
      const int tn = (t + 1 < T_) ? (t + 1) : t;
      const float* src = xrow + (size_t)tn * I_;
      xf0 = *(const floatx4*)(src);
      xf1 = *(const floatx4*)(src + 4);
      xf2 = *(const floatx4*)(src + 32);
      xf3 = *(const floatx4*)(src + 36);
    }

    // issue poll probes BEFORE Phase A so they fly under the MFMAs
    u64* ub = units + (size_t)(t & 1) * UNITS_PER_PARITY + gbase;
    u64* up1 = ub + q1 * 256 + tid;
    u64* up2 = ub + q2 * 256 + tid;
    u64* up3 = ub + q3 * 256 + tid;
    u64 v1 = 0, v2 = 0, v3 = 0;
    if (t > 0) {
      v1 = aload64(up1);
      v2 = aload64(up2);
      v3 = aload64(up3);
    }

    // ---- Phase A: bias + x + OWN quarter (LDS weights, poll shadow) ----
    const unsigned short* hrow = &h_lds[t & 1][mb][0];
    floatx4 acc[4];
#pragma unroll
    for (int j = 0; j < 4; ++j)
      acc[j] = (floatx4){bias[j], bias[j], bias[j], bias[j]};
    MFMA4L(a0, 0)
    MFMA4L(a1, 1)
    { bf16x8 a = HREAD(hb_own, 0); MFMA4L(a, 2) }
    { bf16x8 a = HREAD(hb_own, 1); MFMA4L(a, 3) }

    // ---- quiet pipelined poll for the 3 peer quarters of h_t ----
    if (t > 0) {
      bool ok = ((uint32)(v1 >> 32) == (uint32)t) &
                ((uint32)(v2 >> 32) == (uint32)t) &
                ((uint32)(v3 >> 32) == (uint32)t);
      int it = 0;
      while (!__all(ok) && ++it < SENT_CAP) {
        u64 n1 = 0, n2 = 0, n3 = 0;
        if (!ok) {
          n1 = aload64(up1);
          n2 = aload64(up2);
          n3 = aload64(up3);
        }
        __builtin_amdgcn_s_sleep(1);
        if (!ok) {
          v1 = n1; v2 = n2; v3 = n3;
          ok = ((uint32)(v1 >> 32) == (uint32)t) &
               ((uint32)(v2 >> 32) == (uint32)t) &
               ((uint32)(v3 >> 32) == (uint32)t);
        }
      }
      // capture payloads into current read-buffer (peer cols, disjoint
      // from Phase A's own-col reads)
      unsigned short* hw = &h_lds[t & 1][pm][0];
      *(uint32*)(hw + pc1) = (uint32)v1;
      *(uint32*)(hw + pc2) = (uint32)v2;
      *(uint32*)(hw + pc3) = (uint32)v3;
    }
    __syncthreads();  // MID: peer quarters of buf[t&1] ready

    // ---- Phase C: peer-quarter MFMAs (register weights, serial path) ----
    { bf16x8 a = HREAD(hb1, 0); MFMA4R(a, 0) }
    { bf16x8 a = HREAD(hb1, 1); MFMA4R(a, 1) }
    { bf16x8 a = HREAD(hb2, 0); MFMA4R(a, 2) }
    { bf16x8 a = HREAD(hb2, 1); MFMA4R(a, 3) }
    { bf16x8 a = HREAD(hb3, 0); MFMA4R(a, 4) }
    { bf16x8 a = HREAD(hb3, 1); MFMA4R(a, 5) }

    // ---- in-register nonlinearity + c/h update; publish ASAP ----
    if (lk < 2) {
      floatx4 iv, fv, gv, ov;
#pragma unroll
      for (int r = 0; r < 4; ++r) {
        iv[r] = fast_sig(acc[0][r]);
        fv[r] = fast_sig(acc[1][r]);
        gv[r] = fast_tanh(acc[2][r]);
        ov[r] = fast_sig(acc[3][r]);
      }
      c_reg = fv * c_reg + iv * gv;
#pragma unroll
      for (int r = 0; r < 4; ++r) {
        float hv = ov[r] * fast_tanh(c_reg[r]);
        unsigned short hb = __builtin_bit_cast(unsigned short, (__bf16)hv);
        int pv = __shfl_xor((int)hb, 1);  // partner ln^1, same lk
        if ((ln & 1) == 0) {
          const int m = lk * 4 + r;  // batch row 0..7
          uint32 dword = (uint32)hb | ((uint32)(unsigned short)pv << 16);
          u64 val = (u64)dword | ((u64)(uint32)(t + 1) << 32);
          const size_t uoff = gbase + (size_t)(q * 256 + m * 32 + opair);
          if (t == T_ - 1) {
            // final h -> clean region (never polled, never RMW'd)
            astore64(units + 2 * (size_t)UNITS_PER_PARITY + uoff, val);
          } else {
            astore64(units + (size_t)((t + 1) & 1) * UNITS_PER_PARITY + uoff,
                     val);
            // own quarter -> next read-buffer
            *(uint32*)&h_lds[(t + 1) & 1][m][ocol] = dword;
          }
        }
      }
    }
    __syncthreads();  // END: buf[(t+1)&1] own cols ready for Phase A(t+1)
  }
#undef HREAD
#undef WLD
#undef MFMA4L
#undef MFMA4R
}

// out[b] = dot(h_T[b], fc_w) + fc_b. Final h lives in the clean region at
// offset 2*UPP. Agent loads -> fresh across replays, no flush dependency.
__global__ void lstm_fc(const u64* __restrict__ units,
                        const float* __restrict__ fc_w,
                        const float* __restrict__ fc_b,
                        float* __restrict__ out) {
  const int b = threadIdx.x;
  const int g = b >> 3, m = b & 7;
  const u64* base =
      units + 2 * (size_t)UNITS_PER_PARITY + (size_t)g * UNITS_PER_GROUP;
  float sum = fc_b[0];
#pragma unroll 4
  for (int u = 0; u < 128; ++u) {
    const int qq = u >> 5, p = u & 31;
    u64 v = aload64(base + qq * 256 + m * 32 + p);
    uint32 lo = (uint32)v;
    const int d = qq * QH + 2 * p;
    sum += bf2f(lo & 0xffffu) * fc_w[d] + bf2f(lo >> 16) * fc_w[d + 1];
  }
  out[b] = sum;
}

extern "C" void kernel_launch(void* const* d_in, const int* in_sizes, int n_in,
                              void* d_out, int out_size, void* d_ws,
                              size_t ws_size, hipStream_t stream) {
  const float* x    = (const float*)d_in[0];
  const float* W_ih = (const float*)d_in[1];
  const float* W_hh = (const float*)d_in[2];
  const float* b_ih = (const float*)d_in[3];
  const float* b_hh = (const float*)d_in[4];
  const float* fc_w = (const float*)d_in[5];
  const float* fc_b = (const float*)d_in[6];
  float* out = (float*)d_out;

  u64* units = (u64*)d_ws;  // 2 parities + final region: 3*256KB = 768KB ws
  // tag poison 0xAAAAAAAA != any live tag (1..1024) => no init needed.

  lstm_main<<<dim3(NGROUP * NQ), dim3(256), 0, stream>>>(
      x, W_ih, W_hh, b_ih, b_hh, units);
  lstm_fc<<<dim3(1), dim3(256), 0, stream>>>(units, fc_w, fc_b, out);
}

// Round 13
// 2270.152 us; speedup vs baseline: 1.1163x; 1.1163x over previous
//
#include <hip/hip_runtime.h>
#include <stdint.h>

// LSTM: B=256, T=1024, I=64, H=256, O=1. fp32 in/out, bf16 MFMA internally.
//
// Round-24 = R23 resubmitted verbatim (R23 never ran: GPU acquisition
// timeout). R23 = R11 champion (2223us, verified) + three minimal edits
// that attack the ONLY remaining term. Evidence: R21 (fan-in 3 + overlap,
// 2486us) and R22 (+ no-spill serial path, 2534us) prove step time is
// INSENSITIVE to fan-in, compute overlap, and spill -> the cost is the
// publish->visibility->detect cycle itself (~5200cy/step vs ~900cy
// compute + ~900cy quantization + ~900cy RT = ~2700 explained). Prime
// suspect for the missing ~2500cy: s_sleep(1) wakeup latency (wave
// re-scheduling quantum >> 64cy), paid once per sweep by all threads and
// max-reduced across the block.
//  E1: poll paced by DEPENDENT LOAD LATENCY, no s_sleep. Issue rate = 1
//      load per ~900cy per unsatisfied lane - as quiet as the sleep
//      version (R8/R10's congestion came from continuous multi-in-flight
//      issue, not from this), but with zero wakeup cost.
//  E2: own-slice shortcut. Block s publishes units covering hid
//      32s..32s+31; R11 then re-polled its OWN units through MALL. Now the
//      update phase ALSO writes those pairs directly into h_lds, and the
//      32 threads whose 4 poll units are all own-units skip the poll
//      entirely (ok=true). 1024->896 polled units.
//  E3: acc-init + the 4 x-part MFMAs hoisted above the poll wait (they
//      don't touch h_lds; MFMA pipe is idle during the poll anyway).
// Everything else is byte-identical R11: protocol, publishes, tags,
// parity, poison, dead-latch caps, fc kernel.
//
// Structure (R3/R9/R11 proven): 256 blocks = 32 batch-groups (8 batches) x
// 8 gate-slices (128 gate rows). Weights register-resident as bf16 MFMA
// B-fragments. h published as 8B single-copy-atomic units {2xbf16 h, tag=
// step} via relaxed AGENT-scope (MALL-coherent) stores; consumers poll
// tags directly - no fences, no flags, no producer drain. Parity-reuse
// safety: tag-t units are only overwritten at end of step t+1, which needs
// all peers' poll(t) complete. Tag poison 0xAAAAAAAA never equals live
// tags 1..1024 => no ws init. Dead-latch caps => wrong-answer-not-hang.

#define T_ 1024
#define I_ 64
#define H_ 256
#define NSLICE 8
#define NGROUP 32
#define MB 8      /* batches per group  */
#define HB 32     /* hidden units per block */
#define HROW 272  /* padded h_lds row (ushorts), 544 B = 34 x 16 B */

#define UNITS_PER_GROUP 1024                       /* 8B units per step */
#define UNITS_PER_PARITY (NGROUP * UNITS_PER_GROUP)
#define SENT_CAP (1 << 16)   /* dead-latch: ~64k load-paced sweeps (~25ms) */

typedef float floatx4 __attribute__((ext_vector_type(4)));
typedef __bf16 bf16x8 __attribute__((ext_vector_type(8)));
typedef unsigned short ushortx8 __attribute__((ext_vector_type(8)));
typedef unsigned int uintx4 __attribute__((ext_vector_type(4)));
typedef unsigned int uint32;
typedef unsigned long long u64;

__device__ __forceinline__ float bf2f(uint32 u16) {
  uint32 u = u16 << 16;
  return __builtin_bit_cast(float, u);
}
__device__ __forceinline__ bf16x8 packbf8(floatx4 a, floatx4 b) {
  bf16x8 r;
  r[0] = (__bf16)a[0]; r[1] = (__bf16)a[1];
  r[2] = (__bf16)a[2]; r[3] = (__bf16)a[3];
  r[4] = (__bf16)b[0]; r[5] = (__bf16)b[1];
  r[6] = (__bf16)b[2]; r[7] = (__bf16)b[3];
  return r;
}
__device__ __forceinline__ float fast_sig(float v) {
  return 1.0f / (1.0f + __expf(-v));
}
__device__ __forceinline__ float fast_tanh(float v) {
  float e = __expf(2.0f * v);
  return 1.0f - 2.0f / (e + 1.0f);
}
__device__ __forceinline__ u64 aload64(const u64* p) {
  return __hip_atomic_load(p, __ATOMIC_RELAXED, __HIP_MEMORY_SCOPE_AGENT);
}

__global__ __launch_bounds__(256, 1) void lstm_main(
    const float* __restrict__ x, const float* __restrict__ W_ih,
    const float* __restrict__ W_hh, const float* __restrict__ b_ih,
    const float* __restrict__ b_hh, u64* __restrict__ units) {
  const int tid = threadIdx.x;
  const int bid = blockIdx.x;
  const int s = bid >> 5;     // slice 0..7  (bid%8 == g%8 -> spread XCDs)
  const int g = bid & 31;     // group 0..31
  const int w = tid >> 6;     // wave id == gate type (i,f,g,o)
  const int lane = tid & 63;
  const int ln = lane & 15;   // MFMA n / A m
  const int lk = lane >> 4;   // MFMA k-subgroup (8 elems each)

  __shared__ float xch[4][2][16][8];                     // [gate][j][n][m]
  __shared__ __align__(16) unsigned short h_lds[MB][HROW];

  // zero h_lds (h_0 = 0 for t=0; also clears pad)
  {
    uint32* p = (uint32*)&h_lds[0][0];
    for (int i = tid; i < MB * HROW / 2; i += 256) p[i] = 0u;
  }

  // ---- preload weight B-fragments (bf16) + bias, once ----
  bf16x8 wf[2][10];
  float bias[2];
#pragma unroll
  for (int j = 0; j < 2; ++j) {
    const int row = w * 256 + s * HB + j * 16 + ln;
    bias[j] = b_ih[row] + b_hh[row];
#pragma unroll
    for (int kc = 0; kc < 10; ++kc) {
      const int kk = kc * 32 + lk * 8;
      const float* src = (kk < I_) ? (W_ih + (size_t)row * I_ + kk)
                                   : (W_hh + (size_t)row * H_ + (kk - I_));
      floatx4 f0 = *(const floatx4*)src;
      floatx4 f1 = *(const floatx4*)(src + 4);
      wf[j][kc] = packbf8(f0, f1);
    }
  }

  const int mb = ln & 7;                       // batch row (m>=8 duplicates)
  const float* xrow = x + ((size_t)(g * MB + mb)) * T_ * I_;
  // update-phase roles
  const int um = tid >> 5;                     // 0..7 batch
  const int uh = tid & 31;                     // 0..31 hidden local
  const int uj = uh >> 4, un = uh & 15;
  float c_reg = 0.0f;

  // E2: threads whose 4 poll units are ALL this block's own publishes
  // ((tid&31)>>2 == s <=> unit dwords in [s*16, s*16+16)) skip the poll;
  // those h_lds cols are written locally at update time instead.
  const bool ownthr = (((tid & 31) >> 2) == s);

  const size_t gbase = (size_t)g * UNITS_PER_GROUP;

  __syncthreads();

#pragma unroll 1
  for (int t = 0; t < T_; ++t) {
    // x loads issued first so they overlap the poll
    floatx4 xf0, xf1, xf2, xf3;
    {
      const float* src = xrow + t * I_ + lk * 8;
      xf0 = *(const floatx4*)(src);
      xf1 = *(const floatx4*)(src + 4);
      xf2 = *(const floatx4*)(src + 32);
      xf3 = *(const floatx4*)(src + 36);
    }

    // issue first poll probes BEFORE the x-part MFMAs (E3 overlap)
    const u64* up =
        units + (size_t)(t & 1) * UNITS_PER_PARITY + gbase + tid * 4;
    u64 v0 = 0, v1 = 0, v2 = 0, v3 = 0;
    const bool polling = (t > 0) && !ownthr;
    if (polling) {
      v0 = aload64(up + 0);
      v1 = aload64(up + 1);
      v2 = aload64(up + 2);
      v3 = aload64(up + 3);
    }

    // ---- E3: acc init + x-part MFMAs (no h dependency, poll shadow) ----
    bf16x8 a0 = packbf8(xf0, xf1);
    bf16x8 a1 = packbf8(xf2, xf3);
    floatx4 acc[2];
    acc[0] = (floatx4){bias[0], bias[0], bias[0], bias[0]};
    acc[1] = (floatx4){bias[1], bias[1], bias[1], bias[1]};
    acc[0] = __builtin_amdgcn_mfma_f32_16x16x32_bf16(a0, wf[0][0], acc[0],
                                                     0, 0, 0);
    acc[1] = __builtin_amdgcn_mfma_f32_16x16x32_bf16(a0, wf[1][0], acc[1],
                                                     0, 0, 0);
    acc[0] = __builtin_amdgcn_mfma_f32_16x16x32_bf16(a1, wf[0][1], acc[0],
                                                     0, 0, 0);
    acc[1] = __builtin_amdgcn_mfma_f32_16x16x32_bf16(a1, wf[1][1], acc[1],
                                                     0, 0, 0);

    if (t > 0) {
      // ---- E1: load-latency-paced quiet poll (no s_sleep, no wakeup
      // cost). Each unsatisfied lane issues 1 dependent 32B sweep per ~RT;
      // satisfied lanes issue nothing. Payload captured in the detecting
      // sweep. SENT_CAP dead-latch => wrong-answer-not-hang.
      bool ok = !polling || (((uint32)(v0 >> 32) == (uint32)t) &
                            ((uint32)(v1 >> 32) == (uint32)t) &
                            ((uint32)(v2 >> 32) == (uint32)t) &
                            ((uint32)(v3 >> 32) == (uint32)t));
      int it = 0;
      while (!__all(ok) && ++it < SENT_CAP) {
        if (!ok) {
          v0 = aload64(up + 0);
          v1 = aload64(up + 1);
          v2 = aload64(up + 2);
          v3 = aload64(up + 3);
          ok = ((uint32)(v0 >> 32) == (uint32)t) &
               ((uint32)(v1 >> 32) == (uint32)t) &
               ((uint32)(v2 >> 32) == (uint32)t) &
               ((uint32)(v3 >> 32) == (uint32)t);
        }
      }
      if (polling) {
        uintx4 d;
        d[0] = (uint32)v0; d[1] = (uint32)v1;
        d[2] = (uint32)v2; d[3] = (uint32)v3;
        // unit u = m*128 + dword; tid*4 = (tid>>5)*128 + (tid&31)*4
        uint32* dst = (uint32*)&h_lds[tid >> 5][0] + (tid & 31) * 4;
        *(uintx4*)dst = d;  // 16B aligned
      }
    }
    __syncthreads();  // S1: h_lds ready (capture + own-local from t-1)

    // ---- h-part MFMAs: kc 2..9 from h_lds ----
    const unsigned short* hrow = &h_lds[mb][0];
#pragma unroll
    for (int kc = 2; kc < 10; ++kc) {
      bf16x8 a = __builtin_bit_cast(
          bf16x8, *(const ushortx8*)(hrow + (kc - 2) * 32 + lk * 8));
      acc[0] = __builtin_amdgcn_mfma_f32_16x16x32_bf16(a, wf[0][kc], acc[0],
                                                       0, 0, 0);
      acc[1] = __builtin_amdgcn_mfma_f32_16x16x32_bf16(a, wf[1][kc], acc[1],
                                                       0, 0, 0);
    }

    // ---- nonlinearity (wave-uniform branch) + LDS exchange ----
#pragma unroll
    for (int j = 0; j < 2; ++j) {
      floatx4 v = acc[j];
      if (w == 2) {
        v[0] = fast_tanh(v[0]); v[1] = fast_tanh(v[1]);
        v[2] = fast_tanh(v[2]); v[3] = fast_tanh(v[3]);
      } else {
        v[0] = fast_sig(v[0]); v[1] = fast_sig(v[1]);
        v[2] = fast_sig(v[2]); v[3] = fast_sig(v[3]);
      }
      if (lk < 2) {  // valid m rows 0..7 live in lanes 0..31, m = lk*4+reg
        *(floatx4*)&xch[w][j][ln][lk * 4] = v;
      }
    }
    __syncthreads();  // S2: gates ready

    // ---- c/h update: thread = (um, uh) ----
    float ig = xch[0][uj][un][um];
    float fg = xch[1][uj][un][um];
    float gg = xch[2][uj][un][um];
    float og = xch[3][uj][un][um];
    c_reg = fg * c_reg + ig * gg;
    float hv = og * fast_tanh(c_reg);

    // pair-pack via shfl, publish 8B unit {h pair, tag t+1}; E2: also
    // write the pair locally so next step's MFMA reads it from LDS.
    unsigned short hb = __builtin_bit_cast(unsigned short, (__bf16)hv);
    int pv = __shfl_xor((int)hb, 1);
    if ((uh & 1) == 0) {
      uint32 dword = (uint32)hb | ((uint32)(unsigned short)pv << 16);
      u64 val = (u64)dword | ((u64)(uint32)(t + 1) << 32);
      u64* dst = units + (size_t)((t + 1) & 1) * UNITS_PER_PARITY + gbase +
                 (um * 128 + s * 16 + (uh >> 1));
      __hip_atomic_store(dst, val, __ATOMIC_RELAXED,
                         __HIP_MEMORY_SCOPE_AGENT);
      // own-slice local write (read after S1(t+1); disjoint from capture)
      *(uint32*)&h_lds[um][2 * (s * 16 + (uh >> 1))] = dword;
    }
  }
}

// out[b] = dot(h_T[b], fc_w) + fc_b. Final h = tag-1024 units in parity 0
// ((1023+1)&1 == 0). Bypass loads avoid stale cache lines across replays.
__global__ void lstm_fc(const u64* __restrict__ units,
                        const float* __restrict__ fc_w,
                        const float* __restrict__ fc_b,
                        float* __restrict__ out) {
  const int b = threadIdx.x;
  const int g = b >> 3, m = b & 7;
  const u64* base = units + (size_t)g * UNITS_PER_GROUP + m * 128;
  float sum = fc_b[0];
#pragma unroll 8
  for (int d = 0; d < 128; ++d) {
    u64 v = aload64(base + d);
    uint32 lo = (uint32)v;
    sum += bf2f(lo & 0xffffu) * fc_w[2 * d] + bf2f(lo >> 16) * fc_w[2 * d + 1];
  }
  out[b] = sum;
}

extern "C" void kernel_launch(void* const* d_in, const int* in_sizes, int n_in,
                              void* d_out, int out_size, void* d_ws,
                              size_t ws_size, hipStream_t stream) {
  const float* x    = (const float*)d_in[0];
  const float* W_ih = (const float*)d_in[1];
  const float* W_hh = (const float*)d_in[2];
  const float* b_ih = (const float*)d_in[3];
  const float* b_hh = (const float*)d_in[4];
  const float* fc_w = (const float*)d_in[5];
  const float* fc_b = (const float*)d_in[6];
  float* out = (float*)d_out;

  u64* units = (u64*)d_ws;  // 2 parities x 32 groups x 1024 units x 8B = 512KB
  // tag poison 0xAAAAAAAA != any live tag (1..1024) => no init needed.

  lstm_main<<<dim3(NGROUP * NSLICE), dim3(256), 0, stream>>>(
      x, W_ih, W_hh, b_ih, b_hh, units);
  lstm_fc<<<dim3(1), dim3(256), 0, stream>>>(units, fc_w, fc_b, out);
}